// Round 9
// baseline (120.402 us; speedup 1.0000x reference)
//
#include <hip/hip_runtime.h>
#include <cstdint>

// Attention B=4, S=4096, WORD=512, ED=64, fp32 io. R9 (= R8 + macro fix).
// attn: NO LDS staging, NO barriers. Frag-major K/V/Q layouts make direct
// global->VGPR frag loads 2x512B-contiguous; K/V (4MB) is L2-resident.
// Register ping-pong double-buffer => compiler emits vmcnt(N>0) waits.
// Ksplit 4, grid 512 = 2 blocks/CU, launch_bounds(256,2).

typedef __bf16 bf16x8 __attribute__((ext_vector_type(8)));
typedef float f32x4 __attribute__((ext_vector_type(4)));
typedef float f32x16 __attribute__((ext_vector_type(16)));
typedef int i32x2 __attribute__((ext_vector_type(2)));

#define SCALEQ 0.18033688011112042f  // log2(e)/sqrt(64)

// ws layout (bytes)
#define WT_OFF 0u          // bf16 Wt2 frag-major [12ntg][16kc][64lane][8]
#define Q_OFF  262144u     // bf16 Qf frag-major [512 qtile][8 chunk][32][8]
#define KV_OFF 2359296u    // bf16 kv[256 tiles][8192] (K chunks 0-7, V 8-15)
#define L_OFF  6553600u    // f32 l [4][16384] = 256KB
#define OP_OFF 6815744u    // bf16 op [4][16384][64] = 8MB (ends 15.2MB)

#if defined(__has_builtin)
#if __has_builtin(__builtin_amdgcn_permlane32_swap)
#define HAVE_PLSWAP 1
#endif
#endif
#ifndef HAVE_PLSWAP
#define HAVE_PLSWAP 0
#endif

__device__ __forceinline__ unsigned short bf16_1(float a) {
  unsigned ua = __builtin_bit_cast(unsigned, a);
  ua += 0x7FFFu + ((ua >> 16) & 1u);
  return (unsigned short)(ua >> 16);
}
__device__ __forceinline__ unsigned pk_bf16(float a, float b) {
  unsigned ua = __builtin_bit_cast(unsigned, a);
  unsigned ub = __builtin_bit_cast(unsigned, b);
  ua += 0x7FFFu + ((ua >> 16) & 1u);
  ub += 0x7FFFu + ((ub >> 16) & 1u);
  return (ua >> 16) | (ub & 0xFFFF0000u);
}
__device__ __forceinline__ unsigned pkru(float lo, float hi) {
  unsigned a = __builtin_bit_cast(unsigned, lo) + 0x8000u;
  unsigned b = __builtin_bit_cast(unsigned, hi) + 0x8000u;
  return __builtin_amdgcn_perm(b, a, 0x07060302u);
}
__device__ __forceinline__ void plswap(unsigned& x, unsigned& y, unsigned hl) {
#if HAVE_PLSWAP
  i32x2 r = __builtin_amdgcn_permlane32_swap((int)x, (int)y, false, false);
  x = (unsigned)r[0];
  y = (unsigned)r[1];
#else
  unsigned xs = (unsigned)__shfl_xor((int)x, 32);
  unsigned ys = (unsigned)__shfl_xor((int)y, 32);
  unsigned nx = hl ? ys : x;
  unsigned ny = hl ? y : xs;
  x = nx;
  y = ny;
#endif
}

// ------------- kernel 0: W -> frag-major bf16 Wt2 --------------------------
__global__ __launch_bounds__(256) void prep_w(const float* __restrict__ Wq,
                                              const float* __restrict__ Wk,
                                              const float* __restrict__ Wv,
                                              unsigned short* __restrict__ wt2) {
  unsigned gtid = blockIdx.x * 256u + threadIdx.x;  // 98304
  unsigned mat = gtid >> 15, rem = gtid & 32767u;
  const float* w = (mat == 0) ? Wq : (mat == 1) ? Wk : Wv;
  float v = w[rem];  // coalesced [k][n]
  unsigned k = rem >> 6, n = rem & 63u;
  unsigned col = mat * 64u + n;
  unsigned ntg = col >> 4, l15c = col & 15u;
  unsigned kc = k >> 5, quad = (k >> 3) & 3u, j = k & 7u;
  wt2[((ntg * 16u + kc) * 64u + quad * 16u + l15c) * 8u + j] = bf16_1(v);
}

// ------------- kernel 1: QKV projection (16 rows/block, grid 1024) ---------
__global__ __launch_bounds__(256, 4) void qkv_proj(
    const float* __restrict__ x, const unsigned short* __restrict__ wt2,
    const float* __restrict__ bq, const float* __restrict__ bk,
    const float* __restrict__ bv, unsigned short* __restrict__ qfm,
    unsigned short* __restrict__ kvws) {
  __shared__ __align__(16) char xs[16384];  // 16 rows x 512k bf16 swizzled
  __shared__ float biasl[192];
  const unsigned t = threadIdx.x;
  const unsigned row0 = blockIdx.x * 16u;
  const unsigned w = t >> 6, lane = t & 63u, l15 = lane & 15u, quad = lane >> 4;

  if (t < 192u) {
    unsigned mat = t >> 6, n = t & 63u;
    biasl[t] = (mat == 0) ? bq[n] : (mat == 1) ? bk[n] : bv[n];
  }
#pragma unroll
  for (int i = 0; i < 8; i++) {  // stage x fp32 -> bf16, swizzled
    unsigned idx4 = t + 256u * (unsigned)i;
    unsigned fidx = idx4 * 4u;
    unsigned row = fidx >> 9, k = fidx & 511u, g = k >> 3;
    float4 f = *(const float4*)(x + row0 * 512u + fidx);
    int2 v = make_int2(pkru(f.x, f.y), pkru(f.z, f.w));
    *(int2*)(xs + row * 1024u + ((g ^ (row & 7u)) << 4) + (k & 7u) * 2u) = v;
  }
  __syncthreads();

  f32x4 acc[3];
#pragma unroll
  for (int i = 0; i < 3; i++) acc[i] = {0.f, 0.f, 0.f, 0.f};
  const unsigned arow = l15;
  const unsigned short* wbase = wt2 + (w * 3u * 1024u + lane) * 8u;

  int4 cur[3], nxt[3];
#pragma unroll
  for (int nt = 0; nt < 3; nt++)  // each frag load = 1KB fully contiguous
    cur[nt] = *(const int4*)(wbase + (unsigned)nt * 8192u);
  for (unsigned kc = 0; kc < 16u; kc++) {
    if (kc < 15u) {
#pragma unroll
      for (int nt = 0; nt < 3; nt++)
        nxt[nt] = *(const int4*)(wbase + ((unsigned)nt * 16u + kc + 1u) * 512u);
    }
    unsigned ag = kc * 4u + quad;
    int4 av = *(const int4*)(xs + arow * 1024u + ((ag ^ (arow & 7u)) << 4));
    bf16x8 a = __builtin_bit_cast(bf16x8, av);
#pragma unroll
    for (int nt = 0; nt < 3; nt++)
      acc[nt] = __builtin_amdgcn_mfma_f32_16x16x32_bf16(
          a, __builtin_bit_cast(bf16x8, cur[nt]), acc[nt], 0, 0, 0);
#pragma unroll
    for (int nt = 0; nt < 3; nt++) cur[nt] = nxt[nt];
  }
  unsigned sb = row0 + quad * 4u;
#pragma unroll
  for (int nt = 0; nt < 3; nt++) {
    unsigned col = w * 48u + (unsigned)nt * 16u + l15;
    unsigned mat = col >> 6, n = col & 63u;
    float bb = biasl[col];
    if (mat == 0) {
      // Q frag-major: qfm[q>>5][(n>>4)*2+((n>>3)&1)][q&31][n&7]
      unsigned chunk = (n >> 4) * 2u + ((n >> 3) & 1u);
#pragma unroll
      for (int r = 0; r < 4; r++) {
        unsigned q = sb + (unsigned)r;
        qfm[(q >> 5) * 2048u + chunk * 256u + (q & 31u) * 8u + (n & 7u)] =
            bf16_1((acc[nt][r] + bb) * SCALEQ);
      }
    } else if (mat == 1) {
      // K frag-major: kv[tile][n>>3][kappa][n&7], chunks 0..7
#pragma unroll
      for (int r = 0; r < 4; r++) {
        unsigned s = sb + (unsigned)r;
        unsigned bb2 = s >> 12, tile = (s & 4095u) >> 6, kap = s & 63u;
        kvws[(bb2 * 64u + tile) * 8192u + (n >> 3) * 512u + kap * 8u + (n & 7u)] =
            bf16_1(acc[nt][r] + bb);
      }
    } else {
      // V frag-major: kv[tile][8 + kg][d=n][kappa&7], chunks 8..15
      unsigned s = sb;
      unsigned bb2 = s >> 12, tile = (s & 4095u) >> 6;
      unsigned kg = (s & 63u) >> 3, j0 = s & 7u;
      int2 pv = make_int2(pk_bf16(acc[nt][0] + bb, acc[nt][1] + bb),
                          pk_bf16(acc[nt][2] + bb, acc[nt][3] + bb));
      *(int2*)(kvws + (bb2 * 64u + tile) * 8192u + (8u + kg) * 512u + n * 8u +
               j0) = pv;
    }
  }
}

// ------------- kernel 2: flash attention (Ksplit 4, grid 512) --------------
// Barrier-free: direct global->VGPR frag loads (2x512B segments / instr),
// register ping-pong double buffer, 16 tiles of 64 keys per block.
__global__ __launch_bounds__(256, 2) void attn(
    const unsigned short* __restrict__ qfm,
    const unsigned short* __restrict__ kvws, float* __restrict__ lws,
    unsigned short* __restrict__ opp) {
  __shared__ __align__(16) char sm[34816];  // epilogue transpose only
  const unsigned t = threadIdx.x;
  const unsigned w = t >> 6, lane = t & 63u, l31 = lane & 31u, hl = lane >> 5;
  const unsigned bid = blockIdx.x;
  const unsigned ks = bid >> 7;          // 4 splits
  const unsigned b = (bid >> 5) & 3u;    // 4 batches
  const unsigned qt = bid & 31u;         // 32 q-tiles of 128
  const unsigned q0 = qt * 128u + w * 32u;

  // Q frags (frag-major: contiguous 512B segments)
  const unsigned qtile = b * 128u + qt * 4u + w;
  bf16x8 qf[4];
#pragma unroll
  for (int kq = 0; kq < 4; kq++)
    qf[kq] = __builtin_bit_cast(
        bf16x8, *(const int4*)(qfm + qtile * 2048u +
                               ((unsigned)kq * 2u + hl) * 256u + l31 * 8u));
  f32x16 accO[2];
#pragma unroll
  for (int dh = 0; dh < 2; dh++)
#pragma unroll
    for (int r = 0; r < 16; r++) accO[dh][r] = 0.f;
  float lsum = 0.f;

  // lane-constant offsets (shorts)
  const unsigned short* kvt = kvws + (b * 64u + ks * 16u) * 8192u;
  const unsigned loff = hl * 512u + l31 * 8u;

  int4 bufK[2][8], bufV[2][8];
#define LOADKV(kt_, KB, VB)                                                   \
  do {                                                                        \
    const unsigned short* p = kvt + (kt_)*8192u + loff;                       \
    _Pragma("unroll") for (int i = 0; i < 8; i++) {                           \
      KB[i] = *(const int4*)(p + (unsigned)(i >> 1) * 1024u +                 \
                             (unsigned)(i & 1) * 256u);                       \
      VB[i] = *(const int4*)(p + 4096u + (unsigned)(i >> 1) * 1024u +         \
                             (unsigned)(i & 1) * 256u);                       \
    }                                                                         \
  } while (0)
  LOADKV(0u, bufK[0], bufV[0]);

#pragma unroll 2
  for (unsigned kt = 0; kt < 16u; kt++) {
    const unsigned cb = kt & 1u;
    if (kt < 15u) {
      if (cb == 0u) {
        LOADKV(kt + 1u, bufK[1], bufV[1]);
      } else {
        LOADKV(kt + 1u, bufK[0], bufV[0]);
      }
    }
    const int4* kfr = bufK[cb];
    const int4* vfr = bufV[cb];
#pragma unroll
    for (int kh = 0; kh < 2; kh++) {
      f32x16 z;
#pragma unroll
      for (int r = 0; r < 16; r++) z[r] = 0.f;
#pragma unroll
      for (int kq = 0; kq < 4; kq++)
        z = __builtin_amdgcn_mfma_f32_32x32x16_bf16(
            __builtin_bit_cast(bf16x8, kfr[kq * 2 + kh]), qf[kq], z, 0, 0, 0);
      float lp = 0.f;
#pragma unroll
      for (int r = 0; r < 16; r++) {
        z[r] = __builtin_amdgcn_exp2f(z[r]);
        lp += z[r];
      }
      lsum += lp;
      unsigned pk8[8];
#pragma unroll
      for (int c2 = 0; c2 < 4; c2++) {
        pk8[2 * c2] = pkru(z[4 * c2 + 0], z[4 * c2 + 1]);
        pk8[2 * c2 + 1] = pkru(z[4 * c2 + 2], z[4 * c2 + 3]);
      }
#pragma unroll
      for (int kqpl = 0; kqpl < 2; kqpl++) {
        unsigned a0 = pk8[4 * kqpl + 0], a1 = pk8[4 * kqpl + 1];
        unsigned b0 = pk8[4 * kqpl + 2], b1 = pk8[4 * kqpl + 3];
        plswap(a0, b0, hl);
        plswap(a1, b1, hl);
        int4 fr = make_int4((int)a0, (int)a1, (int)b0, (int)b1);
        bf16x8 pf = __builtin_bit_cast(bf16x8, fr);
        unsigned kqg = (unsigned)kh * 2u + (unsigned)kqpl;
#pragma unroll
        for (int dh = 0; dh < 2; dh++)
          accO[dh] = __builtin_amdgcn_mfma_f32_32x32x16_bf16(
              __builtin_bit_cast(bf16x8, vfr[kqg * 2u + (unsigned)dh]), pf,
              accO[dh], 0, 0, 0);
      }
    }
  }
  // epilogue: l + bf16 O-partials via wave-private LDS transpose (no barrier:
  // each wave's sc region is private)
  float lt = lsum + __shfl_xor(lsum, 32);
  if (hl == 0u) lws[ks * 16384u + b * 4096u + q0 + l31] = lt;
  float* sc = (float*)(sm + w * 8704u);  // 32q x 68 floats
#pragma unroll
  for (int dh = 0; dh < 2; dh++)
#pragma unroll
    for (int r = 0; r < 16; r++) {
      unsigned d = (unsigned)dh * 32u + (unsigned)(r & 3) +
                   8u * (unsigned)(r >> 2) + 4u * hl;
      sc[l31 * 68u + d] = accO[dh][r];
    }
#pragma unroll
  for (int i = 0; i < 4; i++) {
    unsigned ql = (lane >> 3) + (unsigned)i * 8u;
    unsigned d0 = (lane & 7u) * 8u;
    float4 f0 = *(const float4*)(sc + ql * 68u + d0);
    float4 f1 = *(const float4*)(sc + ql * 68u + d0 + 4u);
    int4 pv = make_int4(pkru(f0.x, f0.y), pkru(f0.z, f0.w),
                        pkru(f1.x, f1.y), pkru(f1.z, f1.w));
    *(int4*)(opp + ks * 1048576u + (b * 4096u + q0 + ql) * 64u + d0) = pv;
  }
}

// ------------- kernel 3: combine 4 partials + normalize (grid 512) ---------
__global__ __launch_bounds__(256) void combine(const unsigned short* __restrict__ opp,
                                               const float* __restrict__ lws,
                                               float* __restrict__ out) {
#pragma unroll
  for (int ii = 0; ii < 2; ii++) {
    unsigned slot = blockIdx.x * 512u + threadIdx.x + 256u * (unsigned)ii;
    unsigned q = slot >> 4, c = (slot & 15u) * 4u;
    float l = 0.f;
#pragma unroll
    for (int s = 0; s < 4; s++) l += lws[(unsigned)s * 16384u + q];
    float inv = 1.0f / l;
    float4 r = make_float4(0.f, 0.f, 0.f, 0.f);
#pragma unroll
    for (int s = 0; s < 4; s++) {
      int2 pv = *(const int2*)(opp + (unsigned)s * 1048576u + q * 64u + c);
      r.x += __builtin_bit_cast(float, (unsigned)pv.x << 16);
      r.y += __builtin_bit_cast(float, (unsigned)pv.x & 0xFFFF0000u);
      r.z += __builtin_bit_cast(float, (unsigned)pv.y << 16);
      r.w += __builtin_bit_cast(float, (unsigned)pv.y & 0xFFFF0000u);
    }
    r.x *= inv; r.y *= inv; r.z *= inv; r.w *= inv;
    *(float4*)(out + q * 64u + c) = r;
  }
}

extern "C" void kernel_launch(void* const* d_in, const int* in_sizes, int n_in,
                              void* d_out, int out_size, void* d_ws,
                              size_t ws_size, hipStream_t stream) {
  const float* x = (const float*)d_in[0];
  const float* Wq = (const float*)d_in[1];
  const float* bq = (const float*)d_in[2];
  const float* Wk = (const float*)d_in[3];
  const float* bk = (const float*)d_in[4];
  const float* Wv = (const float*)d_in[5];
  const float* bv = (const float*)d_in[6];
  char* ws = (char*)d_ws;
  unsigned short* wt2 = (unsigned short*)(ws + WT_OFF);
  unsigned short* qb = (unsigned short*)(ws + Q_OFF);
  unsigned short* kvb = (unsigned short*)(ws + KV_OFF);
  float* lp = (float*)(ws + L_OFF);
  unsigned short* opp = (unsigned short*)(ws + OP_OFF);
  float* outp = (float*)d_out;

  prep_w<<<384, 256, 0, stream>>>(Wq, Wk, Wv, wt2);
  qkv_proj<<<1024, 256, 0, stream>>>(x, wt2, bq, bk, bv, qb, kvb);
  attn<<<512, 256, 0, stream>>>(qb, kvb, lp, opp);
  combine<<<512, 256, 0, stream>>>(opp, lp, outp);
}